// Round 10
// baseline (699.781 us; speedup 1.0000x reference)
//
#include <hip/hip_runtime.h>
#include <stdint.h>

typedef unsigned short u16;
typedef _Float16 f16;
typedef f16 f16x8 __attribute__((ext_vector_type(8)));
typedef float f32x16 __attribute__((ext_vector_type(16)));

// Problem constants
#define M_     4
#define B_     256
#define NPG_   64
#define N_     (B_*NPG_)    // 16384
#define DEG_   8
#define E_     (N_*DEG_)    // 131072
#define DF_    16
#define D_     256
#define L_     5
#define NA_    2
#define TASKS_ 10

#define HROW 520            // u16 row stride of split-h buffer (1040 B, 16B aligned)
#define MFMA16(a,b,c) __builtin_amdgcn_mfma_f32_32x32x16_f16(a,b,c,0,0,0)

// ---------------- f16 helpers ----------------
__device__ __forceinline__ u16 h_bits(f16 h) { union { f16 h; u16 u; } c; c.h = h; return c.u; }
__device__ __forceinline__ f16 bits_h(u16 u) { union { u16 u; f16 h; } c; c.u = u; return c.h; }
__device__ __forceinline__ float h2f(u16 u) { return (float)bits_h(u); }
__device__ __forceinline__ void split_f16(float v, u16& hi, u16& lo) {
  f16 h = (f16)v;
  f16 l = (f16)(v - (float)h);
  hi = h_bits(h); lo = h_bits(l);
}

// u16 index of the 8-elem hi group for (row, chunk); lo group at +8. XOR swizzle on chunk.
// (R6 swizzle — R7's variant tripled SQ_LDS_BANK_CONFLICT; kept.)
__device__ __forceinline__ int haddr8(int row, int chunk) {
  return row * HROW + ((chunk ^ (row & 7)) << 4);
}
__device__ __forceinline__ void write_split(u16* hfU, int row, int col, float v) {
  const int ad = haddr8(row, col >> 3) + (col & 7);
  u16 hi, lo; split_f16(v, hi, lo);
  hfU[ad] = hi; hfU[ad + 8] = lo;
}

// ---------------- Threefry-2x32 (exact JAX semantics) ----------------
__device__ __forceinline__ uint32_t rotl32(uint32_t v, int r) { return (v << r) | (v >> (32 - r)); }
__device__ __forceinline__ void threefry2x32(uint32_t k0, uint32_t k1, uint32_t x0, uint32_t x1,
                                             uint32_t& o0, uint32_t& o1) {
  const uint32_t ks2 = k0 ^ k1 ^ 0x1BD11BDAu;
  x0 += k0; x1 += k1;
#define TFR(r) { x0 += x1; x1 = rotl32(x1, r); x1 ^= x0; }
  TFR(13) TFR(15) TFR(26) TFR(6)   x0 += k1;  x1 += ks2 + 1u;
  TFR(17) TFR(29) TFR(16) TFR(24)  x0 += ks2; x1 += k0 + 2u;
  TFR(13) TFR(15) TFR(26) TFR(6)   x0 += k0;  x1 += k1 + 3u;
  TFR(17) TFR(29) TFR(16) TFR(24)  x0 += k1;  x1 += ks2 + 4u;
  TFR(13) TFR(15) TFR(26) TFR(6)   x0 += ks2; x1 += k0 + 5u;
#undef TFR
  o0 = x0; o1 = x1;
}

// =========== 512-thread (mega) full-precision primitives — unchanged from R9 ===========
__device__ __forceinline__ void gemm_w_full(u16* __restrict__ hfU, const u16* __restrict__ WTm,
                                            const float* __restrict__ bias, bool do_relu) {
  const int tid = threadIdx.x;
  const int lane = tid & 63, w = tid >> 6;
  const int l31 = lane & 31, lh = lane >> 5;
  const int col = w * 32 + l31;
  const float bv = bias[col];

  f32x16 acc0 = {}, acc1 = {};
  const u16* Bbase = WTm + col * 8;
#pragma unroll
  for (int ks = 0; ks < 16; ++ks) {
    const int chunk = ks * 2 + lh;                 // k = 8*chunk + e
    const int a0 = haddr8(l31, chunk);
    const int a1 = haddr8(32 + l31, chunk);
    const f16x8 ahi0 = *(const f16x8*)(hfU + a0);
    const f16x8 ahi1 = *(const f16x8*)(hfU + a1);
    const f16x8 alo0 = *(const f16x8*)(hfU + a0 + 8);
    const f16x8 alo1 = *(const f16x8*)(hfU + a1 + 8);
    const f16x8 bh = *(const f16x8*)(Bbase + chunk * 2048);
    const f16x8 bl = *(const f16x8*)(Bbase + chunk * 2048 + 65536);
    acc0 = MFMA16(ahi0, bh, acc0);
    acc0 = MFMA16(ahi0, bl, acc0);
    acc0 = MFMA16(alo0, bh, acc0);
    acc1 = MFMA16(ahi1, bh, acc1);
    acc1 = MFMA16(ahi1, bl, acc1);
    acc1 = MFMA16(alo1, bh, acc1);
  }
  __syncthreads();                       // S1: all A reads done, h region dead
#pragma unroll
  for (int r = 0; r < 16; ++r) {
    const int rr = (r & 3) + 8 * (r >> 2) + 4 * lh;
    float v0 = acc0[r] + bv;
    float v1 = acc1[r] + bv;
    if (do_relu) { v0 = fmaxf(v0, 0.f); v1 = fmaxf(v1, 0.f); }
    write_split(hfU, rr, col, v0);
    write_split(hfU, 32 + rr, col, v1);
  }
  __syncthreads();                       // S2: new h ready
}

__device__ __forceinline__ void gemm_adj_full(u16* __restrict__ hfU, const u16* __restrict__ AdjU,
                                              float epsl) {
  const int tid = threadIdx.x;
  const int lane = tid & 63, w = tid >> 6;
  const int l31 = lane & 31, lh = lane >> 5;
  const int d = w * 32 + l31;
  const int dc = d >> 3, de = d & 7;
  f32x16 acc0 = {}, acc1 = {};
#pragma unroll
  for (int kk = 0; kk < 4; ++kk) {
    const f16x8 A0 = *(const f16x8*)(AdjU + l31 * 72 + (kk * 2 + lh) * 8);
    const f16x8 A1 = *(const f16x8*)(AdjU + (32 + l31) * 72 + (kk * 2 + lh) * 8);
    const int jb = kk * 16 + lh * 8;
    f16x8 bh, bl;
#pragma unroll
    for (int jj = 0; jj < 8; ++jj) {
      const int ad = haddr8(jb + jj, dc) + de;
      bh[jj] = bits_h(hfU[ad]);
      bl[jj] = bits_h(hfU[ad + 8]);
    }
    acc0 = MFMA16(A0, bh, acc0);
    acc1 = MFMA16(A1, bh, acc1);
    acc0 = MFMA16(A0, bl, acc0);
    acc1 = MFMA16(A1, bl, acc1);
  }
  float self0[16], self1[16];
#pragma unroll
  for (int r = 0; r < 16; ++r) {
    const int rr = (r & 3) + 8 * (r >> 2) + 4 * lh;
    { const int ad = haddr8(rr, dc) + de;      self0[r] = h2f(hfU[ad]) + h2f(hfU[ad + 8]); }
    { const int ad = haddr8(32 + rr, dc) + de; self1[r] = h2f(hfU[ad]) + h2f(hfU[ad + 8]); }
  }
  __syncthreads();                       // S1: all reads done
#pragma unroll
  for (int r = 0; r < 16; ++r) {
    const int rr = (r & 3) + 8 * (r >> 2) + 4 * lh;
    write_split(hfU, rr, d, acc0[r] + epsl * self0[r]);
    write_split(hfU, 32 + rr, d, acc1[r] + epsl * self1[r]);
  }
  __syncthreads();                       // S2
}

// 512-thread mindist (mega)
__device__ __forceinline__ void mindist_mfma(u16* __restrict__ hfU, float* __restrict__ mindS) {
  const int tid = threadIdx.x;
  const int lane = tid & 63, w = tid >> 6;
  const int gb = w & 3, gi = gb >> 1, gj = gb & 1, ks = w >> 2;
  const int l31 = lane & 31, lh = lane >> 5;
  f32x16 acc = {};
#pragma unroll
  for (int t = 0; t < 8; ++t) {
    const int chunk = 4 * t + 2 * ks + lh;
    const int ra = haddr8(gi * 32 + l31, chunk);
    const int rb_ = haddr8(gj * 32 + l31, chunk);
    const f16x8 ahi = *(const f16x8*)(hfU + ra);
    const f16x8 alo = *(const f16x8*)(hfU + ra + 8);
    const f16x8 bhi = *(const f16x8*)(hfU + rb_);
    const f16x8 blo = *(const f16x8*)(hfU + rb_ + 8);
    acc = MFMA16(ahi, bhi, acc);
    acc = MFMA16(ahi, blo, acc);
    acc = MFMA16(alo, bhi, acc);
  }
  __syncthreads();                       // S1: h dead
  float* hfF = (float*)hfU;
  if (ks == 1) {
#pragma unroll
    for (int r = 0; r < 16; ++r) {
      const int rr = (r & 3) + 8 * (r >> 2) + 4 * lh;
      hfF[gb * 1088 + rr * 34 + l31] = acc[r];
    }
  }
  __syncthreads();                       // S2
  if (ks == 0) {
#pragma unroll
    for (int r = 0; r < 16; ++r) {
      const int rr = (r & 3) + 8 * (r >> 2) + 4 * lh;
      const float g = acc[r] + hfF[gb * 1088 + rr * 34 + l31];
      hfF[8192 + (gi * 32 + rr) * 66 + gj * 32 + l31] = g;
    }
  }
  __syncthreads();                       // S3
  {
    const int i = tid >> 3, jt = tid & 7;
    const float gii = hfF[8192 + i * 66 + i];
    float dmin = 3.4e38f;
#pragma unroll
    for (int jj = 0; jj < 8; ++jj) {
      const int j = jt * 8 + jj;
      const float gjj = hfF[8192 + j * 66 + j];
      const float gij = hfF[8192 + i * 66 + j];
      float d2 = fmaxf(gii + gjj - 2.f * gij, 0.f);
      if (j == i) d2 += 1e9f;
      dmin = fminf(dmin, d2);
    }
    dmin = fminf(dmin, __shfl_xor(dmin, 1));
    dmin = fminf(dmin, __shfl_xor(dmin, 2));
    dmin = fminf(dmin, __shfl_xor(dmin, 4));
    if (jt == 0) mindS[i] = dmin;
  }
  __syncthreads();                       // S4
}

// =========== mega light phase: hi-plane ping-pong (1 barrier/op) ===========
// pin/pout in {0,8}: byte-plane within each 16-u16 group. Reads Pin, writes Pout
// (disjoint addresses -> no WAR barrier needed; single visibility barrier at end).
__device__ __forceinline__ void gemm_w_light(u16* __restrict__ hfU, const u16* __restrict__ WTm,
                                             const float* __restrict__ bias, bool do_relu,
                                             int pin, int pout) {
  const int tid = threadIdx.x;
  const int lane = tid & 63, w = tid >> 6;
  const int l31 = lane & 31, lh = lane >> 5;
  const int col = w * 32 + l31;
  const float bv = bias[col];
  f32x16 acc0 = {}, acc1 = {};
  const u16* Bbase = WTm + col * 8;
#pragma unroll
  for (int ks = 0; ks < 16; ++ks) {
    const int chunk = ks * 2 + lh;
    const f16x8 a0 = *(const f16x8*)(hfU + haddr8(l31, chunk) + pin);
    const f16x8 a1 = *(const f16x8*)(hfU + haddr8(32 + l31, chunk) + pin);
    const f16x8 bh = *(const f16x8*)(Bbase + chunk * 2048);
    acc0 = MFMA16(a0, bh, acc0);
    acc1 = MFMA16(a1, bh, acc1);
  }
#pragma unroll
  for (int r = 0; r < 16; ++r) {
    const int rr = (r & 3) + 8 * (r >> 2) + 4 * lh;
    float v0 = acc0[r] + bv, v1 = acc1[r] + bv;
    if (do_relu) { v0 = fmaxf(v0, 0.f); v1 = fmaxf(v1, 0.f); }
    hfU[haddr8(rr, col >> 3) + (col & 7) + pout] = h_bits((f16)v0);
    hfU[haddr8(32 + rr, col >> 3) + (col & 7) + pout] = h_bits((f16)v1);
  }
  __syncthreads();
}

__device__ __forceinline__ void gemm_adj_light(u16* __restrict__ hfU, const u16* __restrict__ AdjU,
                                               float epsl, int pin, int pout) {
  const int tid = threadIdx.x;
  const int lane = tid & 63, w = tid >> 6;
  const int l31 = lane & 31, lh = lane >> 5;
  const int d = w * 32 + l31;
  const int dc = d >> 3, de = d & 7;
  f32x16 acc0 = {}, acc1 = {};
#pragma unroll
  for (int kk = 0; kk < 4; ++kk) {
    const f16x8 A0 = *(const f16x8*)(AdjU + l31 * 72 + (kk * 2 + lh) * 8);
    const f16x8 A1 = *(const f16x8*)(AdjU + (32 + l31) * 72 + (kk * 2 + lh) * 8);
    const int jb = kk * 16 + lh * 8;
    f16x8 bh;
#pragma unroll
    for (int jj = 0; jj < 8; ++jj)
      bh[jj] = bits_h(hfU[haddr8(jb + jj, dc) + de + pin]);
    acc0 = MFMA16(A0, bh, acc0);
    acc1 = MFMA16(A1, bh, acc1);
  }
#pragma unroll
  for (int r = 0; r < 16; ++r) {
    const int rr = (r & 3) + 8 * (r >> 2) + 4 * lh;
    const float s0 = h2f(hfU[haddr8(rr, dc) + de + pin]);
    const float s1 = h2f(hfU[haddr8(32 + rr, dc) + de + pin]);
    hfU[haddr8(rr, dc) + de + pout]      = h_bits((f16)(acc0[r] + epsl * s0));
    hfU[haddr8(32 + rr, dc) + de + pout] = h_bits((f16)(acc1[r] + epsl * s1));
  }
  __syncthreads();
}

// =========== 1024-thread (gnn1) k-split primitives ===========
// Coverage (audited): w in [0,16): ks = w>>3 (k-half), cb = w&7 (col-block).
// Tiles (rb,cb): 16, each by 2 waves (ks 0/1) combined via fp32 scratch.
// Chunks: ks*16 + q*2 + lh, q in [0,8) -> ks0: 0..15, ks1: 16..31; union complete, disjoint.
__device__ __forceinline__ void gemm_w3_ks1024(u16* __restrict__ hfU, const u16* __restrict__ WTm,
                                               const float* __restrict__ bias, bool do_relu) {
  const int tid = threadIdx.x;
  const int lane = tid & 63, w = tid >> 6;
  const int l31 = lane & 31, lh = lane >> 5;
  const int ks = w >> 3;
  const int cb = w & 7;
  const int col = cb * 32 + l31;
  const float bv = bias[col];

  f32x16 acc0 = {}, acc1 = {};
  const u16* Bbase = WTm + col * 8;
#pragma unroll
  for (int q = 0; q < 8; ++q) {
    const int chunk = ks * 16 + q * 2 + lh;
    const int a0 = haddr8(l31, chunk);
    const int a1 = haddr8(32 + l31, chunk);
    const f16x8 ahi0 = *(const f16x8*)(hfU + a0);
    const f16x8 ahi1 = *(const f16x8*)(hfU + a1);
    const f16x8 alo0 = *(const f16x8*)(hfU + a0 + 8);
    const f16x8 alo1 = *(const f16x8*)(hfU + a1 + 8);
    const f16x8 bh = *(const f16x8*)(Bbase + chunk * 2048);
    const f16x8 bl = *(const f16x8*)(Bbase + chunk * 2048 + 65536);
    acc0 = MFMA16(ahi0, bh, acc0);
    acc0 = MFMA16(ahi0, bl, acc0);
    acc0 = MFMA16(alo0, bh, acc0);
    acc1 = MFMA16(ahi1, bh, acc1);
    acc1 = MFMA16(ahi1, bl, acc1);
    acc1 = MFMA16(alo1, bh, acc1);
  }
  __syncthreads();                      // S1: all A reads done; h dead
  float* scr = (float*)hfU;             // scratch [cb][row 0..63][l31], 16384 floats <= 16640
  if (ks == 1) {
#pragma unroll
    for (int r = 0; r < 16; ++r) {
      const int rr = (r & 3) + 8 * (r >> 2) + 4 * lh;
      scr[(cb * 64 + rr) * 32 + l31]      = acc0[r];
      scr[(cb * 64 + 32 + rr) * 32 + l31] = acc1[r];
    }
  }
  __syncthreads();                      // S2: partials visible
  float sc0[16], sc1[16];
  if (ks == 0) {
#pragma unroll
    for (int r = 0; r < 16; ++r) {
      const int rr = (r & 3) + 8 * (r >> 2) + 4 * lh;
      sc0[r] = scr[(cb * 64 + rr) * 32 + l31];
      sc1[r] = scr[(cb * 64 + 32 + rr) * 32 + l31];
    }
  }
  __syncthreads();                      // S2b: scratch reads drained before u16 writes
  if (ks == 0) {
#pragma unroll
    for (int r = 0; r < 16; ++r) {
      const int rr = (r & 3) + 8 * (r >> 2) + 4 * lh;
      float v0 = acc0[r] + sc0[r] + bv;
      float v1 = acc1[r] + sc1[r] + bv;
      if (do_relu) { v0 = fmaxf(v0, 0.f); v1 = fmaxf(v1, 0.f); }
      write_split(hfU, rr, col, v0);
      write_split(hfU, 32 + rr, col, v1);
    }
  }
  __syncthreads();                      // S3
}

__device__ __forceinline__ void gemm_adj3_1024(u16* __restrict__ hfU, const u16* __restrict__ AdjU,
                                               float epsl) {
  const int tid = threadIdx.x;
  const int lane = tid & 63, w = tid >> 6;
  const int l31 = lane & 31, lh = lane >> 5;
  const bool act = (w < 8);
  const int d = (w & 7) * 32 + l31;
  const int dc = d >> 3, de = d & 7;
  f32x16 acc0 = {}, acc1 = {};
  float self0[16], self1[16];
  if (act) {
#pragma unroll
    for (int kk = 0; kk < 4; ++kk) {
      const f16x8 A0 = *(const f16x8*)(AdjU + l31 * 72 + (kk * 2 + lh) * 8);
      const f16x8 A1 = *(const f16x8*)(AdjU + (32 + l31) * 72 + (kk * 2 + lh) * 8);
      const int jb = kk * 16 + lh * 8;
      f16x8 bh, bl;
#pragma unroll
      for (int jj = 0; jj < 8; ++jj) {
        const int ad = haddr8(jb + jj, dc) + de;
        bh[jj] = bits_h(hfU[ad]);
        bl[jj] = bits_h(hfU[ad + 8]);
      }
      acc0 = MFMA16(A0, bh, acc0);
      acc1 = MFMA16(A1, bh, acc1);
      acc0 = MFMA16(A0, bl, acc0);
      acc1 = MFMA16(A1, bl, acc1);
    }
#pragma unroll
    for (int r = 0; r < 16; ++r) {
      const int rr = (r & 3) + 8 * (r >> 2) + 4 * lh;
      { const int ad = haddr8(rr, dc) + de;      self0[r] = h2f(hfU[ad]) + h2f(hfU[ad + 8]); }
      { const int ad = haddr8(32 + rr, dc) + de; self1[r] = h2f(hfU[ad]) + h2f(hfU[ad + 8]); }
    }
  }
  __syncthreads();                      // S1
  if (act) {
#pragma unroll
    for (int r = 0; r < 16; ++r) {
      const int rr = (r & 3) + 8 * (r >> 2) + 4 * lh;
      write_split(hfU, rr, d, acc0[r] + epsl * self0[r]);
      write_split(hfU, 32 + rr, d, acc1[r] + epsl * self1[r]);
    }
  }
  __syncthreads();                      // S2
}

__device__ __forceinline__ void mindist_1024(u16* __restrict__ hfU, float* __restrict__ mindS) {
  const int tid = threadIdx.x;
  const int lane = tid & 63, w = tid >> 6;
  const bool act = (w < 8);
  const int gb = w & 3, gi = gb >> 1, gj = gb & 1, ks = (w >> 2) & 1;
  const int l31 = lane & 31, lh = lane >> 5;
  f32x16 acc = {};
  if (act) {
#pragma unroll
    for (int t = 0; t < 8; ++t) {
      const int chunk = 4 * t + 2 * ks + lh;
      const int ra = haddr8(gi * 32 + l31, chunk);
      const int rb_ = haddr8(gj * 32 + l31, chunk);
      const f16x8 ahi = *(const f16x8*)(hfU + ra);
      const f16x8 alo = *(const f16x8*)(hfU + ra + 8);
      const f16x8 bhi = *(const f16x8*)(hfU + rb_);
      const f16x8 blo = *(const f16x8*)(hfU + rb_ + 8);
      acc = MFMA16(ahi, bhi, acc);
      acc = MFMA16(ahi, blo, acc);
      acc = MFMA16(alo, bhi, acc);
    }
  }
  __syncthreads();                      // S1: h dead
  float* hfF = (float*)hfU;
  if (act && ks == 1) {
#pragma unroll
    for (int r = 0; r < 16; ++r) {
      const int rr = (r & 3) + 8 * (r >> 2) + 4 * lh;
      hfF[gb * 1088 + rr * 34 + l31] = acc[r];
    }
  }
  __syncthreads();                      // S2
  if (act && ks == 0) {
#pragma unroll
    for (int r = 0; r < 16; ++r) {
      const int rr = (r & 3) + 8 * (r >> 2) + 4 * lh;
      const float g = acc[r] + hfF[gb * 1088 + rr * 34 + l31];
      hfF[8192 + (gi * 32 + rr) * 66 + gj * 32 + l31] = g;
    }
  }
  __syncthreads();                      // S3
  if (tid < 512) {
    const int i = tid >> 3, jt = tid & 7;
    const float gii = hfF[8192 + i * 66 + i];
    float dmin = 3.4e38f;
#pragma unroll
    for (int jj = 0; jj < 8; ++jj) {
      const int j = jt * 8 + jj;
      const float gjj = hfF[8192 + j * 66 + j];
      const float gij = hfF[8192 + i * 66 + j];
      float d2 = fmaxf(gii + gjj - 2.f * gij, 0.f);
      if (j == i) d2 += 1e9f;
      dmin = fminf(dmin, d2);
    }
    dmin = fminf(dmin, __shfl_xor(dmin, 1));
    dmin = fminf(dmin, __shfl_xor(dmin, 2));
    dmin = fminf(dmin, __shfl_xor(dmin, 4));
    if (jt == 0) mindS[i] = dmin;
  }
  __syncthreads();                      // S4
}

// ---------------- shared staging helpers ----------------
__device__ __forceinline__ void stage_adj(u16* AdjU, const float* AdjF, int b, int tid, int T) {
  const float* src = AdjF + b * 4096;
  for (int t = tid; t < 4096; t += T)
    AdjU[(t >> 6) * 72 + (t & 63)] = h_bits((f16)src[t]);
}

// xcur = tx * anchor_emb[anchor] + tx. WRITE_LO=false for the output-only (light) phase.
template<bool WRITE_LO>
__device__ __forceinline__ void build_xcur(u16* hfU, const float* h0g, const float* aemb,
                                           const int* anchorS, int b, int tid) {
  const int i = tid >> 3, part = tid & 7;
  const float* t = h0g + (b * 64 + i) * 256;
  const float* e = aemb + anchorS[i] * D_;
#pragma unroll
  for (int c = 0; c < 4; ++c) {
    const int chunk = part * 4 + c;
    const float4 tv0 = *(const float4*)(t + chunk * 8);
    const float4 tv1 = *(const float4*)(t + chunk * 8 + 4);
    const float4 ev0 = *(const float4*)(e + chunk * 8);
    const float4 ev1 = *(const float4*)(e + chunk * 8 + 4);
    float vv[8];
    vv[0] = fmaf(tv0.x, ev0.x, tv0.x); vv[1] = fmaf(tv0.y, ev0.y, tv0.y);
    vv[2] = fmaf(tv0.z, ev0.z, tv0.z); vv[3] = fmaf(tv0.w, ev0.w, tv0.w);
    vv[4] = fmaf(tv1.x, ev1.x, tv1.x); vv[5] = fmaf(tv1.y, ev1.y, tv1.y);
    vv[6] = fmaf(tv1.z, ev1.z, tv1.z); vv[7] = fmaf(tv1.w, ev1.w, tv1.w);
    f16x8 hi8, lo8;
#pragma unroll
    for (int ee = 0; ee < 8; ++ee) { u16 h, l; split_f16(vv[ee], h, l); hi8[ee] = bits_h(h); lo8[ee] = bits_h(l); }
    const int a = haddr8(i, chunk);
    *(f16x8*)(hfU + a) = hi8;
    if (WRITE_LO) *(f16x8*)(hfU + a + 8) = lo8;
  }
}

// Gumbel-argmax sampling (exact JAX threefry); updates anchorS. Call with all threads; sync outside.
__device__ __forceinline__ void sample_anchor(const float* mindS, float* scoreS, int* anchorS,
                                              int m, int b, int iter, int tid) {
  if (tid < 64) {
    const int j = tid;
    uint32_t k0, k1;
    threefry2x32(0u, 42u, 0u, (uint32_t)iter, k0, k1);
    const uint32_t p = (uint32_t)(m * (B_ * NPG_) + b * NPG_ + j);
    uint32_t o0, o1, bits;
    if (p < 32768u) { threefry2x32(k0, k1, p, p + 32768u, o0, o1); bits = o0; }
    else            { threefry2x32(k0, k1, p - 32768u, p, o0, o1); bits = o1; }
    const float f = __uint_as_float((bits >> 9) | 0x3f800000u) - 1.0f;
    const float uv = fmaxf(1e-9f, f + 1e-9f);
    const float pred = -mindS[j] - ((anchorS[j] > 0) ? 10.0f : 0.0f);
    scoreS[j] = pred - logf(-logf(uv));
  }
  __syncthreads();
  if (tid == 0) {
    int best = 0; float bv = scoreS[0];
    for (int j = 1; j < 64; ++j) { const float v = scoreS[j]; if (v > bv) { bv = v; best = j; } }
    anchorS[best] = iter;
  }
}

// ---------------- small kernels ----------------
__global__ void build_adj_kernel(const int* __restrict__ esrc, const int* __restrict__ edst,
                                 float* __restrict__ AdjF) {
  const int e = blockIdx.x * 256 + threadIdx.x;
  if (e < E_) {
    const int s = esrc[e];
    const int d = edst[e];
    const int g = s >> 6;
    atomicAdd(AdjF + g * 4096 + (d & 63) * 64 + (s & 63), 1.0f);
  }
}

// Pre-split W (f16 hi/lo): off = (k>>3)*2048 + col*8 + (k&7); lo plane at +65536.
__global__ __launch_bounds__(256) void prep_wt(const float* __restrict__ gW1, const float* __restrict__ gW2,
                                               const float* __restrict__ Wn2n, u16* __restrict__ WTbuf) {
  const int mat = blockIdx.x;
  const float* Wsrc = (mat < 5) ? (gW1 + mat * 65536)
                    : (mat < 10) ? (gW2 + (mat - 5) * 65536) : Wn2n;
  u16* dst = WTbuf + (size_t)mat * 131072;
  const int base = blockIdx.y * 2048;
  for (int idx = base + threadIdx.x; idx < base + 2048; idx += 256) {
    const int k = idx >> 8, d = idx & 255;
    const float a = Wsrc[idx];
    u16 hi, lo; split_f16(a, hi, lo);
    const int off = (k >> 3) * 2048 + d * 8 + (k & 7);
    dst[off] = hi;
    dst[65536 + off] = lo;
  }
}

// ---------------- phase 1: encoder + iter-1 GNN + mindist, once per b (1024 thr, k-split) ------
__global__ __launch_bounds__(1024)
void gnn1_kernel(const float* __restrict__ x, const float* __restrict__ Wenc,
                 const float* __restrict__ benc, float* __restrict__ h0g,
                 const float* __restrict__ AdjF, const u16* __restrict__ WTbuf,
                 const float* __restrict__ gb1, const float* __restrict__ gb2,
                 const float* __restrict__ eps, float* __restrict__ mindG) {
  __shared__ __align__(16) u16 hfU[64 * HROW];
  __shared__ __align__(16) u16 AdjU[64 * 72];
  __shared__ float mindS[64];
  const int tid = threadIdx.x;
  const int b = blockIdx.x;

  // --- fused encoder: h0 = relu(x @ Wenc + benc), Wenc padded stride 264 (R8 fix) ---
  {
    float* scr = (float*)hfU;                 // [0..4223) Wenc, [4300..4556) benc, [4600..5624) x
    for (int t = tid; t < 4096; t += 1024) {
      const int k = t >> 8, d = t & 255;
      scr[k * 264 + d + (d >> 5)] = Wenc[t];
    }
    if (tid < 256) scr[4300 + tid] = benc[tid];
    if (tid < 1024) scr[4600 + tid] = x[b * 1024 + tid];
    __syncthreads();

    const int i = tid >> 4, part = tid & 15;  // 64 rows x 16 d-slices of 16
    float xv[16];
#pragma unroll
    for (int k = 0; k < 16; ++k) xv[k] = scr[4600 + i * 16 + k];
    float hv[16];
#pragma unroll
    for (int dd = 0; dd < 16; ++dd) {
      const int d = part * 16 + dd;
      float acc = scr[4300 + d];
#pragma unroll
      for (int k = 0; k < 16; ++k) acc = fmaf(xv[k], scr[k * 264 + d + (d >> 5)], acc);
      hv[dd] = fmaxf(acc, 0.f);
    }
    float* dst = h0g + (b * 64 + i) * 256 + part * 16;
#pragma unroll
    for (int dd = 0; dd < 16; dd += 4) {
      float4 v; v.x = hv[dd]; v.y = hv[dd + 1]; v.z = hv[dd + 2]; v.w = hv[dd + 3];
      *(float4*)(dst + dd) = v;
    }
    __syncthreads();                          // scratch reads done before u16 writes
#pragma unroll
    for (int c = 0; c < 2; ++c) {             // 2 chunks of 8 per thread
      f16x8 hi8, lo8;
#pragma unroll
      for (int e = 0; e < 8; ++e) { u16 h, l; split_f16(hv[c * 8 + e], h, l); hi8[e] = bits_h(h); lo8[e] = bits_h(l); }
      const int a = haddr8(i, part * 2 + c);
      *(f16x8*)(hfU + a) = hi8;
      *(f16x8*)(hfU + a + 8) = lo8;
    }
  }
  stage_adj(AdjU, AdjF, b, tid, 1024);
  __syncthreads();

  for (int l = 0; l < L_; ++l) {
    const float epsl = 1.0f + eps[l];
    gemm_adj3_1024(hfU, AdjU, epsl);
    gemm_w3_ks1024(hfU, WTbuf + (size_t)l * 131072,       gb1 + l * D_, true);
    gemm_w3_ks1024(hfU, WTbuf + (size_t)(5 + l) * 131072, gb2 + l * D_, true);
  }
  mindist_1024(hfU, mindS);
  if (tid < 64) mindG[b * 64 + tid] = mindS[tid];
}

// ---------------- phase 2: per (b,m) — sample a1, iters 2..3, head ----------------
__global__ __launch_bounds__(512, 4)
void mega_kernel(const float* __restrict__ h0g, const float* __restrict__ AdjF,
                 const u16* __restrict__ WTbuf,
                 const float* __restrict__ gb1, const float* __restrict__ gb2,
                 const float* __restrict__ eps, const float* __restrict__ aemb,
                 const float* __restrict__ bn2n,
                 const float* __restrict__ Wpred, const float* __restrict__ bpred,
                 const float* __restrict__ mindG, float* __restrict__ outp) {
  __shared__ __align__(16) u16 hfU[64 * HROW];   // 66560 B split-h (also scratch when dead)
  __shared__ __align__(16) u16 AdjU[64 * 72];    //  9216 B f16 adjacency counts
  __shared__ float mindS[64];
  __shared__ float scoreS[64];
  __shared__ float hgS[256];
  __shared__ int   anchorS[64];

  const int tid = threadIdx.x;
  const int b = blockIdx.x;
  const int m = blockIdx.y;

  stage_adj(AdjU, AdjF, b, tid, 512);
  if (tid < 64) { anchorS[tid] = 0; mindS[tid] = mindG[b * 64 + tid]; }
  __syncthreads();

  // iter-1 sampling from precomputed mindist
  sample_anchor(mindS, scoreS, anchorS, m, b, 1, tid);
  __syncthreads();
  build_xcur<true>(hfU, h0g, aemb, anchorS, b, tid);
  __syncthreads();

  // ----- iter 2: full-precision GNN (feeds argmax) -----
  for (int l = 0; l < L_; ++l) {
    const float epsl = 1.0f + eps[l];
    gemm_adj_full(hfU, AdjU, epsl);
    gemm_w_full(hfU, WTbuf + (size_t)l * 131072,       gb1 + l * D_, true);
    gemm_w_full(hfU, WTbuf + (size_t)(5 + l) * 131072, gb2 + l * D_, true);
  }
  mindist_mfma(hfU, mindS);
  sample_anchor(mindS, scoreS, anchorS, m, b, 2, tid);
  __syncthreads();
  build_xcur<false>(hfU, h0g, aemb, anchorS, b, tid);   // light phase: plane 0 only
  __syncthreads();

  // ----- iter 3 + n2n: 1-term f16, plane ping-pong (1 barrier/op) -----
  int p = 0;
  for (int l = 0; l < L_; ++l) {
    const float epsl = 1.0f + eps[l];
    gemm_adj_light(hfU, AdjU, epsl, p, 8 - p); p = 8 - p;
    gemm_w_light(hfU, WTbuf + (size_t)l * 131072,       gb1 + l * D_, true, p, 8 - p); p = 8 - p;
    gemm_w_light(hfU, WTbuf + (size_t)(5 + l) * 131072, gb2 + l * D_, true, p, 8 - p); p = 8 - p;
  }
  gemm_w_light(hfU, WTbuf + (size_t)10 * 131072, bn2n, true, p, 8 - p); p = 8 - p;
  // after 16 toggles p == 0: final hn in plane 0

  if (tid < 256) {
    const int dc = tid >> 3, de = tid & 7;
    float s = 0.f;
    for (int i = 0; i < 64; ++i)
      s += h2f(hfU[haddr8(i, dc) + de]);
    hgS[tid] = s * (1.0f / 64.0f);
  }
  __syncthreads();
  if (tid < 160) {
    const int t = tid >> 4, part = tid & 15;
    float s = 0.f;
    for (int d = part * 16; d < part * 16 + 16; ++d) s = fmaf(hgS[d], Wpred[d * TASKS_ + t], s);
    s += __shfl_xor(s, 1); s += __shfl_xor(s, 2); s += __shfl_xor(s, 4); s += __shfl_xor(s, 8);
    if (part == 0) {
      float val = s * 0.25f;
      if (m == 0) val += bpred[t];
      atomicAdd(outp + b * TASKS_ + t, val);
    }
  }
}

// ---------------- launch ----------------
extern "C" void kernel_launch(void* const* d_in, const int* in_sizes, int n_in,
                              void* d_out, int out_size, void* d_ws, size_t ws_size,
                              hipStream_t stream) {
  const float* x     = (const float*)d_in[0];
  const float* Wenc  = (const float*)d_in[1];
  const float* benc  = (const float*)d_in[2];
  const float* gW1   = (const float*)d_in[3];
  const float* gb1   = (const float*)d_in[4];
  const float* gW2   = (const float*)d_in[5];
  const float* gb2   = (const float*)d_in[6];
  const float* eps   = (const float*)d_in[7];
  const float* aemb  = (const float*)d_in[8];
  const float* Wn2n  = (const float*)d_in[9];
  const float* bn2n  = (const float*)d_in[10];
  const float* Wpred = (const float*)d_in[11];
  const float* bpred = (const float*)d_in[12];
  const int* esrc    = (const int*)d_in[13];
  const int* edst    = (const int*)d_in[14];
  float* outp = (float*)d_out;

  float* h0g  = (float*)d_ws;                      // 16 MB
  float* AdjF = h0g + (size_t)N_ * D_;             // 4 MB
  u16* WTbuf  = (u16*)(AdjF + B_ * 4096);          // 11 * 256 KB f16 split weights
  float* mindG = (float*)(WTbuf + (size_t)11 * 131072);   // B*64 floats

  hipMemsetAsync(AdjF, 0, (size_t)B_ * 4096 * sizeof(float), stream);
  hipMemsetAsync(outp, 0, (size_t)out_size * sizeof(float), stream);
  build_adj_kernel<<<dim3((E_ + 255) / 256), dim3(256), 0, stream>>>(esrc, edst, AdjF);
  prep_wt<<<dim3(11, 32), dim3(256), 0, stream>>>(gW1, gW2, Wn2n, WTbuf);
  gnn1_kernel<<<dim3(B_), dim3(1024), 0, stream>>>(x, Wenc, benc, h0g, AdjF, WTbuf,
                                                   gb1, gb2, eps, mindG);
  mega_kernel<<<dim3(B_, M_), dim3(512), 0, stream>>>(h0g, AdjF, WTbuf, gb1, gb2,
                                                      eps, aemb, bn2n, Wpred, bpred, mindG, outp);
}

// Round 11
// 669.139 us; speedup vs baseline: 1.0458x; 1.0458x over previous
//
#include <hip/hip_runtime.h>
#include <stdint.h>

typedef unsigned short u16;
typedef _Float16 f16;
typedef f16 f16x8 __attribute__((ext_vector_type(8)));
typedef float f32x16 __attribute__((ext_vector_type(16)));

// Problem constants
#define M_     4
#define B_     256
#define NPG_   64
#define N_     (B_*NPG_)    // 16384
#define DEG_   8
#define E_     (N_*DEG_)    // 131072
#define DF_    16
#define D_     256
#define L_     5
#define NA_    2
#define TASKS_ 10

#define HROW 520            // u16 row stride of split-h buffer (1040 B, 16B aligned)
#define MFMA16(a,b,c) __builtin_amdgcn_mfma_f32_32x32x16_f16(a,b,c,0,0,0)

// ---------------- f16 helpers ----------------
__device__ __forceinline__ u16 h_bits(f16 h) { union { f16 h; u16 u; } c; c.h = h; return c.u; }
__device__ __forceinline__ f16 bits_h(u16 u) { union { u16 u; f16 h; } c; c.u = u; return c.h; }
__device__ __forceinline__ float h2f(u16 u) { return (float)bits_h(u); }
__device__ __forceinline__ void split_f16(float v, u16& hi, u16& lo) {
  f16 h = (f16)v;
  f16 l = (f16)(v - (float)h);
  hi = h_bits(h); lo = h_bits(l);
}

// u16 index of the 8-elem hi group for (row, chunk); lo group at +8. XOR swizzle on chunk.
// (R6 swizzle — R7's variant tripled SQ_LDS_BANK_CONFLICT; kept.)
__device__ __forceinline__ int haddr8(int row, int chunk) {
  return row * HROW + ((chunk ^ (row & 7)) << 4);
}
__device__ __forceinline__ void write_split(u16* hfU, int row, int col, float v) {
  const int ad = haddr8(row, col >> 3) + (col & 7);
  u16 hi, lo; split_f16(v, hi, lo);
  hfU[ad] = hi; hfU[ad + 8] = lo;
}
__device__ __forceinline__ void write_hi(u16* hfU, int row, int col, float v) {
  const int ad = haddr8(row, col >> 3) + (col & 7);
  hfU[ad] = h_bits((f16)v);
}

// ---------------- Threefry-2x32 (exact JAX semantics) ----------------
__device__ __forceinline__ uint32_t rotl32(uint32_t v, int r) { return (v << r) | (v >> (32 - r)); }
__device__ __forceinline__ void threefry2x32(uint32_t k0, uint32_t k1, uint32_t x0, uint32_t x1,
                                             uint32_t& o0, uint32_t& o1) {
  const uint32_t ks2 = k0 ^ k1 ^ 0x1BD11BDAu;
  x0 += k0; x1 += k1;
#define TFR(r) { x0 += x1; x1 = rotl32(x1, r); x1 ^= x0; }
  TFR(13) TFR(15) TFR(26) TFR(6)   x0 += k1;  x1 += ks2 + 1u;
  TFR(17) TFR(29) TFR(16) TFR(24)  x0 += ks2; x1 += k0 + 2u;
  TFR(13) TFR(15) TFR(26) TFR(6)   x0 += k0;  x1 += k1 + 3u;
  TFR(17) TFR(29) TFR(16) TFR(24)  x0 += k1;  x1 += ks2 + 4u;
  TFR(13) TFR(15) TFR(26) TFR(6)   x0 += ks2; x1 += k0 + 5u;
#undef TFR
  o0 = x0; o1 = x1;
}

// ---------------- MFMA gemm: h = relu?(h @ W + b), in-place on split-h ----------------
// Wave w owns col-block w (cols 32w..32w+31) for BOTH row-blocks; full K.
// B read from global (L2-resident), each W frag exactly once per block.
// WTm layout (u16): off = hilo*65536 + (k>>3)*2048 + col*8 + (k&7).
// TERMS=3: ahi*(bh+bl)+alo*bh. TERMS=1: ahi*bh, epilogue writes hi plane only.
template<int TERMS>
__device__ __forceinline__ void gemm_w_mfma(u16* __restrict__ hfU, const u16* __restrict__ WTm,
                                            const float* __restrict__ bias, bool do_relu) {
  const int tid = threadIdx.x;
  const int lane = tid & 63, w = tid >> 6;
  const int l31 = lane & 31, lh = lane >> 5;
  const int col = w * 32 + l31;
  const float bv = bias[col];

  f32x16 acc0 = {}, acc1 = {};
  const u16* Bbase = WTm + col * 8;
#pragma unroll
  for (int ks = 0; ks < 16; ++ks) {
    const int chunk = ks * 2 + lh;                 // k = 8*chunk + e
    const int a0 = haddr8(l31, chunk);
    const int a1 = haddr8(32 + l31, chunk);
    const f16x8 ahi0 = *(const f16x8*)(hfU + a0);
    const f16x8 ahi1 = *(const f16x8*)(hfU + a1);
    const f16x8 bh = *(const f16x8*)(Bbase + chunk * 2048);
    if (TERMS == 3) {
      const f16x8 alo0 = *(const f16x8*)(hfU + a0 + 8);
      const f16x8 alo1 = *(const f16x8*)(hfU + a1 + 8);
      const f16x8 bl = *(const f16x8*)(Bbase + chunk * 2048 + 65536);
      acc0 = MFMA16(ahi0, bh, acc0);
      acc0 = MFMA16(ahi0, bl, acc0);
      acc0 = MFMA16(alo0, bh, acc0);
      acc1 = MFMA16(ahi1, bh, acc1);
      acc1 = MFMA16(ahi1, bl, acc1);
      acc1 = MFMA16(alo1, bh, acc1);
    } else {
      acc0 = MFMA16(ahi0, bh, acc0);
      acc1 = MFMA16(ahi1, bh, acc1);
    }
  }
  __syncthreads();                       // S1: all A reads done, h region dead
#pragma unroll
  for (int r = 0; r < 16; ++r) {
    const int rr = (r & 3) + 8 * (r >> 2) + 4 * lh;
    float v0 = acc0[r] + bv;
    float v1 = acc1[r] + bv;
    if (do_relu) { v0 = fmaxf(v0, 0.f); v1 = fmaxf(v1, 0.f); }
    if (TERMS == 3) {
      write_split(hfU, rr, col, v0);       // rows 0..31
      write_split(hfU, 32 + rr, col, v1);  // rows 32..63
    } else {
      write_hi(hfU, rr, col, v0);
      write_hi(hfU, 32 + rr, col, v1);
    }
  }
  __syncthreads();                       // S2: new h ready
}

// ---------------- GIN aggregation via MFMA: h = Adj@h + (1+eps)h, in-place ----------------
// Wave w owns d-block w for BOTH row-blocks. TERMS=1: hi-only gather/self/write.
template<int TERMS>
__device__ __forceinline__ void gemm_adj_mfma(u16* __restrict__ hfU, const u16* __restrict__ AdjU,
                                              float epsl) {
  const int tid = threadIdx.x;
  const int lane = tid & 63, w = tid >> 6;
  const int l31 = lane & 31, lh = lane >> 5;
  const int d = w * 32 + l31;
  const int dc = d >> 3, de = d & 7;
  f32x16 acc0 = {}, acc1 = {};
#pragma unroll
  for (int kk = 0; kk < 4; ++kk) {
    const f16x8 A0 = *(const f16x8*)(AdjU + l31 * 72 + (kk * 2 + lh) * 8);
    const f16x8 A1 = *(const f16x8*)(AdjU + (32 + l31) * 72 + (kk * 2 + lh) * 8);
    const int jb = kk * 16 + lh * 8;
    f16x8 bh, bl;
#pragma unroll
    for (int jj = 0; jj < 8; ++jj) {
      const int j = jb + jj;
      const int ad = haddr8(j, dc) + de;
      bh[jj] = bits_h(hfU[ad]);
      if (TERMS == 3) bl[jj] = bits_h(hfU[ad + 8]);
    }
    acc0 = MFMA16(A0, bh, acc0);
    acc1 = MFMA16(A1, bh, acc1);
    if (TERMS == 3) {
      acc0 = MFMA16(A0, bl, acc0);
      acc1 = MFMA16(A1, bl, acc1);
    }
  }
  // self term (1+eps)*h, read before h is overwritten
  float self0[16], self1[16];
#pragma unroll
  for (int r = 0; r < 16; ++r) {
    const int rr = (r & 3) + 8 * (r >> 2) + 4 * lh;
    { const int ad = haddr8(rr, dc) + de;
      self0[r] = (TERMS == 3) ? (h2f(hfU[ad]) + h2f(hfU[ad + 8])) : h2f(hfU[ad]); }
    { const int ad = haddr8(32 + rr, dc) + de;
      self1[r] = (TERMS == 3) ? (h2f(hfU[ad]) + h2f(hfU[ad + 8])) : h2f(hfU[ad]); }
  }
  __syncthreads();                       // S1: all reads done
#pragma unroll
  for (int r = 0; r < 16; ++r) {
    const int rr = (r & 3) + 8 * (r >> 2) + 4 * lh;
    if (TERMS == 3) {
      write_split(hfU, rr, d, acc0[r] + epsl * self0[r]);
      write_split(hfU, 32 + rr, d, acc1[r] + epsl * self1[r]);
    } else {
      write_hi(hfU, rr, d, acc0[r] + epsl * self0[r]);
      write_hi(hfU, 32 + rr, d, acc1[r] + epsl * self1[r]);
    }
  }
  __syncthreads();                       // S2
}

// ---------------- mindist via Gram matrix G = h h^T (MFMA), h dead afterwards ----------------
__device__ __forceinline__ void mindist_mfma(u16* __restrict__ hfU, float* __restrict__ mindS) {
  const int tid = threadIdx.x;
  const int lane = tid & 63, w = tid >> 6;
  const int gb = w & 3, gi = gb >> 1, gj = gb & 1, ks = w >> 2;
  const int l31 = lane & 31, lh = lane >> 5;
  f32x16 acc = {};
#pragma unroll
  for (int t = 0; t < 8; ++t) {
    const int chunk = 4 * t + 2 * ks + lh;
    const int ra = haddr8(gi * 32 + l31, chunk);
    const int rb_ = haddr8(gj * 32 + l31, chunk);
    const f16x8 ahi = *(const f16x8*)(hfU + ra);
    const f16x8 alo = *(const f16x8*)(hfU + ra + 8);
    const f16x8 bhi = *(const f16x8*)(hfU + rb_);
    const f16x8 blo = *(const f16x8*)(hfU + rb_ + 8);
    acc = MFMA16(ahi, bhi, acc);
    acc = MFMA16(ahi, blo, acc);
    acc = MFMA16(alo, bhi, acc);
  }
  __syncthreads();                       // S1: h dead
  float* hfF = (float*)hfU;
  if (ks == 1) {
#pragma unroll
    for (int r = 0; r < 16; ++r) {
      const int rr = (r & 3) + 8 * (r >> 2) + 4 * lh;
      hfF[gb * 1088 + rr * 34 + l31] = acc[r];
    }
  }
  __syncthreads();                       // S2
  if (ks == 0) {
#pragma unroll
    for (int r = 0; r < 16; ++r) {
      const int rr = (r & 3) + 8 * (r >> 2) + 4 * lh;
      const float g = acc[r] + hfF[gb * 1088 + rr * 34 + l31];
      hfF[8192 + (gi * 32 + rr) * 66 + gj * 32 + l31] = g;
    }
  }
  __syncthreads();                       // S3
  {
    const int i = tid >> 3, jt = tid & 7;
    const float gii = hfF[8192 + i * 66 + i];
    float dmin = 3.4e38f;
#pragma unroll
    for (int jj = 0; jj < 8; ++jj) {
      const int j = jt * 8 + jj;
      const float gjj = hfF[8192 + j * 66 + j];
      const float gij = hfF[8192 + i * 66 + j];
      float d2 = fmaxf(gii + gjj - 2.f * gij, 0.f);
      if (j == i) d2 += 1e9f;
      dmin = fminf(dmin, d2);
    }
    dmin = fminf(dmin, __shfl_xor(dmin, 1));
    dmin = fminf(dmin, __shfl_xor(dmin, 2));
    dmin = fminf(dmin, __shfl_xor(dmin, 4));
    if (jt == 0) mindS[i] = dmin;
  }
  __syncthreads();                       // S4
}

// ---------------- shared staging helpers ----------------
__device__ __forceinline__ void stage_adj(u16* AdjU, const float* AdjF, int b, int tid) {
  const float* src = AdjF + b * 4096;
  for (int t = tid; t < 4096; t += 512)
    AdjU[(t >> 6) * 72 + (t & 63)] = h_bits((f16)src[t]);
}

// xcur = tx * anchor_emb[anchor] + tx. WRITE_LO=false for the output-only (light) phase.
template<bool WRITE_LO>
__device__ __forceinline__ void build_xcur(u16* hfU, const float* h0g, const float* aemb,
                                           const int* anchorS, int b, int tid) {
  const int i = tid >> 3, part = tid & 7;
  const float* t = h0g + (b * 64 + i) * 256;
  const float* e = aemb + anchorS[i] * D_;
#pragma unroll
  for (int c = 0; c < 4; ++c) {
    const int chunk = part * 4 + c;
    const float4 tv0 = *(const float4*)(t + chunk * 8);
    const float4 tv1 = *(const float4*)(t + chunk * 8 + 4);
    const float4 ev0 = *(const float4*)(e + chunk * 8);
    const float4 ev1 = *(const float4*)(e + chunk * 8 + 4);
    float vv[8];
    vv[0] = fmaf(tv0.x, ev0.x, tv0.x); vv[1] = fmaf(tv0.y, ev0.y, tv0.y);
    vv[2] = fmaf(tv0.z, ev0.z, tv0.z); vv[3] = fmaf(tv0.w, ev0.w, tv0.w);
    vv[4] = fmaf(tv1.x, ev1.x, tv1.x); vv[5] = fmaf(tv1.y, ev1.y, tv1.y);
    vv[6] = fmaf(tv1.z, ev1.z, tv1.z); vv[7] = fmaf(tv1.w, ev1.w, tv1.w);
    f16x8 hi8, lo8;
#pragma unroll
    for (int ee = 0; ee < 8; ++ee) { u16 h, l; split_f16(vv[ee], h, l); hi8[ee] = bits_h(h); lo8[ee] = bits_h(l); }
    const int a = haddr8(i, chunk);
    *(f16x8*)(hfU + a) = hi8;
    if (WRITE_LO) *(f16x8*)(hfU + a + 8) = lo8;
  }
}

// Gumbel-argmax sampling (exact JAX threefry); updates anchorS. Call with all threads; sync outside.
__device__ __forceinline__ void sample_anchor(const float* mindS, float* scoreS, int* anchorS,
                                              int m, int b, int iter, int tid) {
  if (tid < 64) {
    const int j = tid;
    uint32_t k0, k1;
    threefry2x32(0u, 42u, 0u, (uint32_t)iter, k0, k1);
    const uint32_t p = (uint32_t)(m * (B_ * NPG_) + b * NPG_ + j);
    uint32_t o0, o1, bits;
    if (p < 32768u) { threefry2x32(k0, k1, p, p + 32768u, o0, o1); bits = o0; }
    else            { threefry2x32(k0, k1, p - 32768u, p, o0, o1); bits = o1; }
    const float f = __uint_as_float((bits >> 9) | 0x3f800000u) - 1.0f;
    const float uv = fmaxf(1e-9f, f + 1e-9f);
    const float pred = -mindS[j] - ((anchorS[j] > 0) ? 10.0f : 0.0f);
    scoreS[j] = pred - logf(-logf(uv));
  }
  __syncthreads();
  if (tid == 0) {
    int best = 0; float bv = scoreS[0];
    for (int j = 1; j < 64; ++j) { const float v = scoreS[j]; if (v > bv) { bv = v; best = j; } }
    anchorS[best] = iter;
  }
}

// ---------------- small kernels ----------------
__global__ void build_adj_kernel(const int* __restrict__ esrc, const int* __restrict__ edst,
                                 float* __restrict__ AdjF) {
  const int e = blockIdx.x * 256 + threadIdx.x;
  if (e < E_) {
    const int s = esrc[e];
    const int d = edst[e];
    const int g = s >> 6;
    atomicAdd(AdjF + g * 4096 + (d & 63) * 64 + (s & 63), 1.0f);
  }
}

// Pre-split W (f16 hi/lo): off = (k>>3)*2048 + col*8 + (k&7); lo plane at +65536.
__global__ __launch_bounds__(256) void prep_wt(const float* __restrict__ gW1, const float* __restrict__ gW2,
                                               const float* __restrict__ Wn2n, u16* __restrict__ WTbuf) {
  const int mat = blockIdx.x;
  const float* Wsrc = (mat < 5) ? (gW1 + mat * 65536)
                    : (mat < 10) ? (gW2 + (mat - 5) * 65536) : Wn2n;
  u16* dst = WTbuf + (size_t)mat * 131072;
  const int base = blockIdx.y * 2048;
  for (int idx = base + threadIdx.x; idx < base + 2048; idx += 256) {
    const int k = idx >> 8, d = idx & 255;
    const float a = Wsrc[idx];
    u16 hi, lo; split_f16(a, hi, lo);
    const int off = (k >> 3) * 2048 + d * 8 + (k & 7);
    dst[off] = hi;
    dst[65536 + off] = lo;
  }
}

// ---------------- phase 1: encoder + iter-1 GNN + mindist, m-invariant -> once per b ----------------
__global__ __launch_bounds__(512)
void gnn1_kernel(const float* __restrict__ x, const float* __restrict__ Wenc,
                 const float* __restrict__ benc, float* __restrict__ h0g,
                 const float* __restrict__ AdjF, const u16* __restrict__ WTbuf,
                 const float* __restrict__ gb1, const float* __restrict__ gb2,
                 const float* __restrict__ eps, float* __restrict__ mindG) {
  __shared__ __align__(16) u16 hfU[64 * HROW];
  __shared__ __align__(16) u16 AdjU[64 * 72];
  __shared__ float mindS[64];
  const int tid = threadIdx.x;
  const int b = blockIdx.x;

  // --- fused encoder: h0 = relu(x @ Wenc + benc) for this graph's 64 nodes ---
  // Wenc staged padded with ROW STRIDE 264 (max intra-row offset 255+7=262 < 264;
  // R8's stride 260 made rows overlap -> 3 corrupted weight columns -> argmax flip).
  {
    float* scr = (float*)hfU;                 // [0..4223) Wenc, [4300..4556) benc, [4600..5624) x
    for (int t = tid; t < 4096; t += 512) {
      const int k = t >> 8, d = t & 255;
      scr[k * 264 + d + (d >> 5)] = Wenc[t];
    }
    if (tid < 256) scr[4300 + tid] = benc[tid];
    for (int t = tid; t < 1024; t += 512) scr[4600 + t] = x[b * 1024 + t];
    __syncthreads();

    const int i = tid >> 3, part = tid & 7;
    float xv[16];
#pragma unroll
    for (int k = 0; k < 16; ++k) xv[k] = scr[4600 + i * 16 + k];
    float hv[32];
#pragma unroll
    for (int dd = 0; dd < 32; ++dd) {
      const int d = part * 32 + dd;
      float acc = scr[4300 + d];
#pragma unroll
      for (int k = 0; k < 16; ++k) acc = fmaf(xv[k], scr[k * 264 + d + (d >> 5)], acc);
      hv[dd] = fmaxf(acc, 0.f);
    }
    // write h0g (coalesced float4) for mega's build_xcur
    float* dst = h0g + (b * 64 + i) * 256 + part * 32;
#pragma unroll
    for (int dd = 0; dd < 32; dd += 4) {
      float4 v; v.x = hv[dd]; v.y = hv[dd + 1]; v.z = hv[dd + 2]; v.w = hv[dd + 3];
      *(float4*)(dst + dd) = v;
    }
    __syncthreads();                          // scratch reads done before u16 writes
    // split-write h0 into hfU from registers
#pragma unroll
    for (int c = 0; c < 4; ++c) {
      f16x8 hi8, lo8;
#pragma unroll
      for (int e = 0; e < 8; ++e) { u16 h, l; split_f16(hv[c * 8 + e], h, l); hi8[e] = bits_h(h); lo8[e] = bits_h(l); }
      const int a = haddr8(i, part * 4 + c);
      *(f16x8*)(hfU + a) = hi8;
      *(f16x8*)(hfU + a + 8) = lo8;
    }
  }
  stage_adj(AdjU, AdjF, b, tid);
  __syncthreads();

  for (int l = 0; l < L_; ++l) {
    const float epsl = 1.0f + eps[l];
    gemm_adj_mfma<3>(hfU, AdjU, epsl);
    gemm_w_mfma<3>(hfU, WTbuf + (size_t)l * 131072,       gb1 + l * D_, true);
    gemm_w_mfma<3>(hfU, WTbuf + (size_t)(5 + l) * 131072, gb2 + l * D_, true);
  }
  mindist_mfma(hfU, mindS);
  if (tid < 64) mindG[b * 64 + tid] = mindS[tid];
}

// ---------------- phase 2: per (b,m) — sample a1, iters 2..3, head ----------------
__global__ __launch_bounds__(512, 4)
void mega_kernel(const float* __restrict__ h0g, const float* __restrict__ AdjF,
                 const u16* __restrict__ WTbuf,
                 const float* __restrict__ gb1, const float* __restrict__ gb2,
                 const float* __restrict__ eps, const float* __restrict__ aemb,
                 const float* __restrict__ bn2n,
                 const float* __restrict__ Wpred, const float* __restrict__ bpred,
                 const float* __restrict__ mindG, float* __restrict__ outp) {
  __shared__ __align__(16) u16 hfU[64 * HROW];   // 66560 B split-h (also scratch when dead)
  __shared__ __align__(16) u16 AdjU[64 * 72];    //  9216 B f16 adjacency counts
  __shared__ float mindS[64];
  __shared__ float scoreS[64];
  __shared__ float hgS[256];
  __shared__ int   anchorS[64];

  const int tid = threadIdx.x;
  const int b = blockIdx.x;
  const int m = blockIdx.y;

  stage_adj(AdjU, AdjF, b, tid);
  if (tid < 64) { anchorS[tid] = 0; mindS[tid] = mindG[b * 64 + tid]; }
  __syncthreads();

  // iter-1 sampling from precomputed mindist
  sample_anchor(mindS, scoreS, anchorS, m, b, 1, tid);
  __syncthreads();
  build_xcur<true>(hfU, h0g, aemb, anchorS, b, tid);
  __syncthreads();

  // ----- iter 2: full-precision GNN (feeds argmax) -----
  for (int l = 0; l < L_; ++l) {
    const float epsl = 1.0f + eps[l];
    gemm_adj_mfma<3>(hfU, AdjU, epsl);
    gemm_w_mfma<3>(hfU, WTbuf + (size_t)l * 131072,       gb1 + l * D_, true);
    gemm_w_mfma<3>(hfU, WTbuf + (size_t)(5 + l) * 131072, gb2 + l * D_, true);
  }
  mindist_mfma(hfU, mindS);
  sample_anchor(mindS, scoreS, anchorS, m, b, 2, tid);
  __syncthreads();
  build_xcur<false>(hfU, h0g, aemb, anchorS, b, tid);   // light phase: hi plane only
  __syncthreads();

  // ----- iter 3: output-path GNN, 1-term f16 hi-only (tolerance is bf16-scale) -----
  for (int l = 0; l < L_; ++l) {
    const float epsl = 1.0f + eps[l];
    gemm_adj_mfma<1>(hfU, AdjU, epsl);
    gemm_w_mfma<1>(hfU, WTbuf + (size_t)l * 131072,       gb1 + l * D_, true);
    gemm_w_mfma<1>(hfU, WTbuf + (size_t)(5 + l) * 131072, gb2 + l * D_, true);
  }

  // ----- head: hn = relu(h @ W_n2n + b_n2n) (1-term), graph mean (hi), pred -----
  gemm_w_mfma<1>(hfU, WTbuf + (size_t)10 * 131072, bn2n, true);
  if (tid < 256) {
    const int dc = tid >> 3, de = tid & 7;
    float s = 0.f;
    for (int i = 0; i < 64; ++i)
      s += h2f(hfU[haddr8(i, dc) + de]);
    hgS[tid] = s * (1.0f / 64.0f);
  }
  __syncthreads();
  if (tid < 160) {
    const int t = tid >> 4, part = tid & 15;
    float s = 0.f;
    for (int d = part * 16; d < part * 16 + 16; ++d) s = fmaf(hgS[d], Wpred[d * TASKS_ + t], s);
    s += __shfl_xor(s, 1); s += __shfl_xor(s, 2); s += __shfl_xor(s, 4); s += __shfl_xor(s, 8);
    if (part == 0) {
      float val = s * 0.25f;
      if (m == 0) val += bpred[t];
      atomicAdd(outp + b * TASKS_ + t, val);
    }
  }
}

// ---------------- launch ----------------
extern "C" void kernel_launch(void* const* d_in, const int* in_sizes, int n_in,
                              void* d_out, int out_size, void* d_ws, size_t ws_size,
                              hipStream_t stream) {
  const float* x     = (const float*)d_in[0];
  const float* Wenc  = (const float*)d_in[1];
  const float* benc  = (const float*)d_in[2];
  const float* gW1   = (const float*)d_in[3];
  const float* gb1   = (const float*)d_in[4];
  const float* gW2   = (const float*)d_in[5];
  const float* gb2   = (const float*)d_in[6];
  const float* eps   = (const float*)d_in[7];
  const float* aemb  = (const float*)d_in[8];
  const float* Wn2n  = (const float*)d_in[9];
  const float* bn2n  = (const float*)d_in[10];
  const float* Wpred = (const float*)d_in[11];
  const float* bpred = (const float*)d_in[12];
  const int* esrc    = (const int*)d_in[13];
  const int* edst    = (const int*)d_in[14];
  float* outp = (float*)d_out;

  float* h0g  = (float*)d_ws;                      // 16 MB
  float* AdjF = h0g + (size_t)N_ * D_;             // 4 MB
  u16* WTbuf  = (u16*)(AdjF + B_ * 4096);          // 11 * 256 KB f16 split weights
  float* mindG = (float*)(WTbuf + (size_t)11 * 131072);   // B*64 floats

  hipMemsetAsync(AdjF, 0, (size_t)B_ * 4096 * sizeof(float), stream);
  hipMemsetAsync(outp, 0, (size_t)out_size * sizeof(float), stream);
  build_adj_kernel<<<dim3((E_ + 255) / 256), dim3(256), 0, stream>>>(esrc, edst, AdjF);
  prep_wt<<<dim3(11, 32), dim3(256), 0, stream>>>(gW1, gW2, Wn2n, WTbuf);
  gnn1_kernel<<<dim3(B_), dim3(512), 0, stream>>>(x, Wenc, benc, h0g, AdjF, WTbuf,
                                                  gb1, gb2, eps, mindG);
  mega_kernel<<<dim3(B_, M_), dim3(512), 0, stream>>>(h0g, AdjF, WTbuf, gb1, gb2,
                                                      eps, aemb, bn2n, Wpred, bpred, mindG, outp);
}